// Round 5
// baseline (2169.308 us; speedup 1.0000x reference)
//
#include <hip/hip_runtime.h>
#include <math.h>

#define HILB 4096
#define FEAT 256
#define OUTW 4098          // 4096 probs + entropy + entangle
#define NBIS 28

typedef float2 cplx;

__device__ __forceinline__ float rl(float v, int l) {
    return __int_as_float(__builtin_amdgcn_readlane(__float_as_int(v), l));
}
__device__ __forceinline__ float sanout(float v) {
    return (v == v && fabsf(v) < 1e30f) ? v : 1e6f;  // readable failure signature
}
__device__ __forceinline__ float wsum(float v) {
    #pragma unroll
    for (int off = 1; off < 64; off <<= 1) v += __shfl_xor(v, off, 64);
    return v;
}

// Block = 1 wave (64 threads) = 1 batch row. Lane i owns row i of G.
// LDS: MA holds amps M (stride-66 float2, 16B-aligned rows), later overlaid
// with G (stride-65 float2: row & column accesses both conflict-free).
__launch_bounds__(64, 1)
__global__ void qsp_kernel(const float* __restrict__ X,  const float* __restrict__ W1,
                           const float* __restrict__ B1, const float* __restrict__ W2,
                           const float* __restrict__ B2, const float* __restrict__ EP,
                           float* __restrict__ out)
{
    __shared__ __align__(16) float MA[64 * 66 * 2];   // 33792 B
    __shared__ float sx[FEAT];
    __shared__ float sh[48];

    const int q  = threadIdx.x;       // lane
    const int bb = blockIdx.x;

    // ---------- stage x row ----------
    *(float4*)(sx + q * 4) = *(const float4*)(X + (size_t)bb * FEAT + q * 4);
    __syncthreads();

    // ---------- h = tanh(x@W1+b1) on lanes 0..47 ; gate product T on lane 63 ----------
    float t00r=0,t00i=0,t01r=0,t01i=0,t10r=0,t10i=0,t11r=0,t11i=0;
    if (q < 48) {
        float acc = B1[q];
        #pragma unroll 4
        for (int t = 0; t < FEAT; ++t) acc += sx[t] * W1[t * 48 + q];
        sh[q] = tanhf(acc);
    } else if (q == 63) {
        t00r = 1.f; t11r = 1.f;
        for (int g = 0; g < 33; ++g) {
            int d = g / 11, gq = g % 11;
            const float* p = EP + (d * 12 + gq) * 4;
            float th = p[0], ph = p[1], la = p[2], ga = p[3];
            float c  = cosf(0.5f * th), sn = sinf(0.5f * th);
            float ephr = cosf(ph), ephi = sinf(ph);
            float elar = cosf(la), elai = sinf(la);
            float egar = cosf(ga), egai = sinf(ga);
            // R = [[c, -e^{i la} s], [e^{i ph} s, e^{i ga} c]]
            float r00r =  c,          r00i = 0.f;
            float r01r = -elar * sn,  r01i = -elai * sn;
            float r10r =  ephr * sn,  r10i =  ephi * sn;
            float r11r =  egar * c,   r11i =  egai * c;
            float n00r = t00r*r00r - t00i*r00i + t01r*r10r - t01i*r10i;
            float n00i = t00r*r00i + t00i*r00r + t01r*r10i + t01i*r10r;
            float n01r = t00r*r01r - t00i*r01i + t01r*r11r - t01i*r11i;
            float n01i = t00r*r01i + t00i*r01r + t01r*r11i + t01i*r11r;
            float n10r = t10r*r00r - t10i*r00i + t11r*r10r - t11i*r10i;
            float n10i = t10r*r00i + t10i*r00r + t11r*r10i + t11i*r10r;
            float n11r = t10r*r01r - t10i*r01i + t11r*r11r - t11i*r11i;
            float n11i = t10r*r01i + t10i*r01r + t11r*r11i + t11i*r11r;
            t00r=n00r; t00i=n00i; t01r=n01r; t01i=n01i;
            t10r=n10r; t10i=n10i; t11r=n11r; t11i=n11i;
        }
    }
    __syncthreads();

    // ---------- GEMM: lane q computes column q of M (64 rows), ssq along the way ----------
    float ssq = 0.f;
    {
        cplx* M2 = (cplx*)MA;
        for (int r = 0; r < 64; ++r) {
            int j = r * 64 + q;
            float re = B2[j], im = B2[HILB + j];
            const float* Wr = W2 + j;
            #pragma unroll 8
            for (int k = 0; k < 48; ++k) {
                float hk = sh[k];
                re += hk * Wr[k * 8192];
                im += hk * Wr[k * 8192 + HILB];
            }
            if (r == 0) {   // apply gate-chain product T to psi0, psi1 (pure shuffles)
                float T00r = rl(t00r,63), T00i = rl(t00i,63), T01r = rl(t01r,63), T01i = rl(t01i,63);
                float T10r = rl(t10r,63), T10i = rl(t10i,63), T11r = rl(t11r,63), T11i = rl(t11i,63);
                float s0r = rl(re,0), s0i = rl(im,0), s1r = rl(re,1), s1i = rl(im,1);
                float n0r = s0r*T00r - s0i*T00i + s1r*T10r - s1i*T10i;
                float n0i = s0r*T00i + s0i*T00r + s1r*T10i + s1i*T10r;
                float n1r = s0r*T01r - s0i*T01i + s1r*T11r - s1i*T11i;
                float n1i = s0r*T01i + s0i*T01r + s1r*T11i + s1i*T11r;
                if (q == 0)      { re = n0r; im = n0i; }
                else if (q == 1) { re = n1r; im = n1i; }
            }
            ssq += re * re + im * im;
            M2[r * 66 + q] = make_float2(re, im);
        }
    }
    __syncthreads();   // M visible to all lanes

    // ---------- norm, entropy, probs (single write) ----------
    float tot  = wsum(ssq);
    float inv  = 1.f / fmaxf(sqrtf(tot), 1e-12f);
    float inv2 = inv * inv;
    if (q == 0) {
        float lam0 = fmaxf(tot * inv2, 1e-12f);
        out[(size_t)bb * OUTW + HILB] = sanout(-lam0 * logf(lam0) + 1.1314877e-7f);
    }
    {
        const cplx* M2 = (const cplx*)MA;
        for (int r = 0; r < 64; ++r) {
            cplx m = M2[r * 66 + q];
            out[(size_t)bb * OUTW + r * 64 + q] = sanout(inv2 * (m.x * m.x + m.y * m.y));
        }
    }

    // ---------- G = inv2 * M^H M accumulated in registers (lane q owns column q) ----------
    float gr[64], gi[64];
    #pragma unroll
    for (int p = 0; p < 64; ++p) { gr[p] = 0.f; gi[p] = 0.f; }
    {
        const cplx* M2 = (const cplx*)MA;
        for (int r = 0; r < 64; ++r) {
            cplx zq = M2[r * 66 + q];
            const float4* mrow = (const float4*)(MA + r * 132);  // broadcast reads
            #pragma unroll
            for (int p2 = 0; p2 < 32; ++p2) {
                float4 mm = mrow[p2];   // (re_p, im_p, re_{p+1}, im_{p+1})
                int p = 2 * p2;
                gr[p]   += mm.x * zq.x + mm.y * zq.y;   // Re(conj(m_p) m_q)
                gi[p]   += mm.x * zq.y - mm.y * zq.x;   // Im(conj(m_p) m_q)
                gr[p+1] += mm.z * zq.x + mm.w * zq.y;
                gi[p+1] += mm.z * zq.y - mm.w * zq.x;
            }
        }
    }
    __syncthreads();   // all M reads done; safe to overlay G
    cplx* GA = (cplx*)MA;              // stride 65
    #pragma unroll
    for (int p = 0; p < 64; ++p) GA[p * 65 + q] = make_float2(gr[p] * inv2, gi[p] * inv2);
    __syncthreads();   // G rows complete

    // ---------- wave-synchronous Householder tridiagonalization (no barriers) ----------
    cplx* row = GA + q * 65;           // lane q owns row q
    float esqv = 0.f;                  // lane i holds |e_i|^2
    for (int k = 0; k < 62; ++k) {
        const int a = k + 1;
        cplx g = row[k];               // own-row element of column k
        const bool act = (q >= a);
        float sig = wsum(act ? (g.x * g.x + g.y * g.y) : 0.f);
        float x1r = rl(g.x, a), x1i = rl(g.y, a);
        float ax1 = sqrtf(x1r * x1r + x1i * x1i);
        float nrm = sqrtf(sig);
        float tau = 0.f, phr = 1.f, phi = 0.f;
        if (sig > 1e-30f) {
            tau = 1.f / (sig + nrm * ax1);
            if (ax1 > 1e-30f) { float ir = 1.f / ax1; phr = x1r * ir; phi = x1i * ir; }
        }
        float vr = act ? g.x : 0.f, vi = act ? g.y : 0.f;
        if (q == a) { vr += phr * nrm; vi += phi * nrm; esqv = sig; }

        // p_i = tau * sum_j G[i][j] v_j   (v_j = 0 for j < a pads the first block)
        float p0r = 0.f, p0i = 0.f, p1r = 0.f, p1i = 0.f;
        for (int j0 = a & ~3; j0 < 64; j0 += 4) {
            #pragma unroll
            for (int u = 0; u < 4; u += 2) {
                int j = j0 + u;
                float vjr = rl(vr, j), vji = rl(vi, j);
                cplx gj = row[j];
                p0r += gj.x * vjr - gj.y * vji;
                p0i += gj.x * vji + gj.y * vjr;
                float vkr = rl(vr, j + 1), vki = rl(vi, j + 1);
                cplx gk = row[j + 1];
                p1r += gk.x * vkr - gk.y * vki;
                p1i += gk.x * vki + gk.y * vkr;
            }
        }
        float pr = tau * (p0r + p1r), pi = tau * (p0i + p1i);
        float K  = 0.5f * tau * wsum(vr * pr + vi * pi);   // inactive lanes have v=0
        float wr = pr - K * vr, wi = pi - K * vi;

        // rank-2 update on active rows: G[i][j] -= v_i conj(w_j) + w_i conj(v_j)
        if (act) {
            for (int j0 = a & ~3; j0 < 64; j0 += 4) {
                #pragma unroll
                for (int u = 0; u < 4; ++u) {
                    int j = j0 + u;
                    float vjr = rl(vr, j), vji = rl(vi, j);
                    float wjr = rl(wr, j), wji = rl(wi, j);
                    cplx gj = row[j];
                    gj.x -= vr * wjr + vi * wji + wr * vjr + wi * vji;
                    gj.y -= vi * wjr - vr * wji + wi * vjr - wr * vji;
                    row[j] = gj;
                }
            }
        }
    }
    float diagv = row[q].x;
    if (q == 63) { cplx ge = row[62]; esqv = ge.x * ge.x + ge.y * ge.y; }

    // ---------- Sturm bisection: lane t finds t-th smallest eigenvalue ----------
    float lo = -0.02f, hi = 1.02f;     // PSD, trace 1
    for (int it = 0; it < NBIS; ++it) {
        float mid = 0.5f * (lo + hi);
        int cnt = 0;
        float qq = rl(diagv, 0) - mid;
        cnt += (qq < 0.f);
        #pragma unroll
        for (int i = 1; i < 64; ++i) {
            float di = rl(diagv, i), ei = rl(esqv, i);
            float aq = (fabsf(qq) < 1e-18f) ? copysignf(1e-18f, qq) : qq;
            qq = di - mid - __fdividef(ei, aq);
            cnt += (qq < 0.f);
        }
        if (cnt > q) hi = mid; else lo = mid;
    }
    float lam  = fmaxf(0.5f * (lo + hi), 1e-24f);
    float term = -lam * logf(lam);
    #pragma unroll
    for (int off = 32; off; off >>= 1) term += __shfl_down(term, off, 64);
    if (q == 0) out[(size_t)bb * OUTW + HILB + 1] = sanout(term);
}

extern "C" void kernel_launch(void* const* d_in, const int* in_sizes, int n_in,
                              void* d_out, int out_size, void* d_ws, size_t ws_size,
                              hipStream_t stream) {
    const float* X  = (const float*)d_in[0];
    const float* W1 = (const float*)d_in[1];
    const float* B1 = (const float*)d_in[2];
    const float* W2 = (const float*)d_in[3];
    const float* B2 = (const float*)d_in[4];
    const float* EP = (const float*)d_in[5];
    qsp_kernel<<<dim3(4096), dim3(64), 0, stream>>>(X, W1, B1, W2, B2, EP, (float*)d_out);
}